// Round 3
// baseline (1408.913 us; speedup 1.0000x reference)
//
#include <hip/hip_runtime.h>
#include <math.h>

#define L_LEN 4500
#define T2 128
#define NT2 36    // ceil(4500/128)
#define TRT 32    // l-span per tile in routing kernels
#define NTT 141   // ceil(4500/32)
#define SPL 16    // l-splits for gram_k
#define OSPL 32   // l-splits for out_k

// ---------------- prep: transpose conv2 weights to [cin][g][k] ----------------
__global__ void prep_w2t_k(const float* __restrict__ w2, float* __restrict__ w2t) {
    int i = blockIdx.x * 256 + threadIdx.x;
    if (i < 64 * 64 * 5) {
        int k = i / 320;
        int r = i - k * 320;
        int c = r / 5;
        int g = r - c * 5;
        w2t[(c * 5 + g) * 64 + k] = w2[i];
    }
}

// ---------------- conv1: x (64,1,L) -> h1 (64,64,L), k=7, SAME ----------------
__global__ __launch_bounds__(256) void conv1_k(const float* __restrict__ x,
                                               const float* __restrict__ w1,
                                               float* __restrict__ h1) {
    int n = blockIdx.x >> 6, k = blockIdx.x & 63;
    float w[7];
#pragma unroll
    for (int g = 0; g < 7; ++g) w[g] = w1[k * 7 + g];
    const float* xr = x + (size_t)n * L_LEN;
    float* hr = h1 + ((size_t)n * 64 + k) * L_LEN;
    for (int l = threadIdx.x; l < L_LEN; l += 256) {
        float a = 0.f;
#pragma unroll
        for (int g = 0; g < 7; ++g) {
            int p = l + g - 3;
            if (p >= 0 && p < L_LEN) a += w[g] * xr[p];
        }
        hr[l] = a;
    }
}

// ------- conv2: h1 (64,64,L) -> h2 (64,64,L), k=5, SAME; + sumsq atomics ------
__global__ __launch_bounds__(256) void conv2_k(const float* __restrict__ h1,
                                               const float* __restrict__ w2t,
                                               float* __restrict__ h2,
                                               float* __restrict__ sq) {
    __shared__ float h1s[64][T2 + 4];
    __shared__ float sqred[4][64];
    int n = blockIdx.x / NT2;
    int t = blockIdx.x - n * NT2;
    int l0 = t * T2;
    const float* h1n = h1 + (size_t)n * 64 * L_LEN;
    for (int idx = threadIdx.x; idx < 64 * (T2 + 4); idx += 256) {
        int ci = idx / (T2 + 4);
        int j = idx - ci * (T2 + 4);
        int l = l0 + j - 2;
        h1s[ci][j] = (l >= 0 && l < L_LEN) ? h1n[(size_t)ci * L_LEN + l] : 0.f;
    }
    __syncthreads();
    int k = threadIdx.x & 63;
    int lg = threadIdx.x >> 6;
    int base = lg * 32;
    float acc[32];
#pragma unroll
    for (int m = 0; m < 32; ++m) acc[m] = 0.f;
    for (int ci = 0; ci < 64; ++ci) {
        const float* wr = w2t + ci * 320 + k;
        float w0 = wr[0], w1 = wr[64], w2v = wr[128], w3 = wr[192], w4 = wr[256];
        float v[36];
#pragma unroll
        for (int j = 0; j < 36; ++j) v[j] = h1s[ci][base + j];
#pragma unroll
        for (int m = 0; m < 32; ++m)
            acc[m] += w0 * v[m] + w1 * v[m + 1] + w2v * v[m + 2] + w3 * v[m + 3] + w4 * v[m + 4];
    }
    float s = 0.f;
    float* h2r = h2 + ((size_t)n * 64 + k) * L_LEN;
#pragma unroll
    for (int m = 0; m < 32; ++m) {
        int l = l0 + base + m;
        if (l < L_LEN) { h2r[l] = acc[m]; s += acc[m] * acc[m]; }
    }
    sqred[lg][k] = s;
    __syncthreads();
    if (threadIdx.x < 64) {
        float tot = sqred[0][threadIdx.x] + sqred[1][threadIdx.x] +
                    sqred[2][threadIdx.x] + sqred[3][threadIdx.x];
        atomicAdd(&sq[n * 64 + threadIdx.x], tot);
    }
}

// ------ gram_k: per (n, l-split) accumulate Gram M[36] for all 64 channels ----
// c = tid&63 (lane -> channel, LDS reads wave-broadcast), sub = tid>>6
// NO dynamic indexing into register arrays (tail handled by unrolled masking).
__global__ __launch_bounds__(256) void gram_k(const float* __restrict__ h2,
                                              const float* __restrict__ sq,
                                              const float* __restrict__ wA,
                                              const float* __restrict__ bA,
                                              float* __restrict__ Mpart) {
    __shared__ __align__(16) float hs[64 * 36];   // row stride 36, j in [0,34): l0+j-1
    __shared__ float Msh[4][64][36];
    __shared__ float invsh[64];
    int n = blockIdx.x / SPL;
    int s = blockIdx.x - n * SPL;
    int c = threadIdx.x & 63;
    int sub = threadIdx.x >> 6;
    if (threadIdx.x < 64) invsh[threadIdx.x] = 1.f / (1.f + sq[n * 64 + threadIdx.x]);
    float wreg[24];
#pragma unroll
    for (int q = 0; q < 24; ++q) wreg[q] = wA[c * 24 + q];
    float biasc = bA[c];
    const float* h2n = h2 + (size_t)n * 64 * L_LEN;
    float M[36];
#pragma unroll
    for (int q = 0; q < 36; ++q) M[q] = 0.f;
    int lsub = sub * 8;

    for (int t = s; t < NTT; t += SPL) {
        int l0 = t * TRT;
        __syncthreads();
        for (int idx = threadIdx.x; idx < 64 * 34; idx += 256) {
            int qr = idx / 34;
            int j = idx - qr * 34;
            int l = l0 + j - 1;
            hs[qr * 36 + j] = (l >= 0 && l < L_LEN) ? h2n[(size_t)qr * L_LEN + l] * invsh[qr] : 0.f;
        }
        __syncthreads();
        int lbase = l0 + lsub;           // wave-uniform
        if (lbase < L_LEN) {
            float H[64];                 // H[i*8+m], all indices compile-time
#pragma unroll
            for (int q = 0; q < 64; ++q) H[q] = biasc;
#pragma unroll
            for (int i = 0; i < 8; ++i) {
#pragma unroll
                for (int p = 0; p < 8; ++p) {
                    const float* r = &hs[(8 * i + p) * 36 + lsub];
                    float4 ra = *(const float4*)r;
                    float4 rb = *(const float4*)(r + 4);
                    float2 rc = *(const float2*)(r + 8);
                    float rr[10] = {ra.x, ra.y, ra.z, ra.w, rb.x, rb.y, rb.z, rb.w, rc.x, rc.y};
                    float w0 = wreg[p * 3], w1 = wreg[p * 3 + 1], w2v = wreg[p * 3 + 2];
#pragma unroll
                    for (int m = 0; m < 8; ++m)
                        H[i * 8 + m] += w0 * rr[m] + w1 * rr[m + 1] + w2v * rr[m + 2];
                }
            }
            if (lbase + 8 > L_LEN) {     // wave-uniform tail: zero invalid columns
#pragma unroll
                for (int m = 0; m < 8; ++m) {
                    if (lbase + m >= L_LEN) {
#pragma unroll
                        for (int i = 0; i < 8; ++i) H[i * 8 + m] = 0.f;
                    }
                }
            }
            int idx2 = 0;
#pragma unroll
            for (int i = 0; i < 8; ++i)
#pragma unroll
                for (int j = i; j < 8; ++j, ++idx2) {
                    float a = 0.f;
#pragma unroll
                    for (int m = 0; m < 8; ++m) a += H[i * 8 + m] * H[j * 8 + m];
                    M[idx2] += a;
                }
        }
    }
    __syncthreads();
#pragma unroll
    for (int q = 0; q < 36; ++q) Msh[sub][c][q] = M[q];
    __syncthreads();
    for (int idx = threadIdx.x; idx < 64 * 36; idx += 256) {
        int cc = idx / 36;
        int q = idx - cc * 36;
        float tot = Msh[0][cc][q] + Msh[1][cc][q] + Msh[2][cc][q] + Msh[3][cc][q];
        Mpart[(((size_t)n * SPL + s) * 64 + cc) * 36 + q] = tot;
    }
}

// ---------- coeff_k: reduce Mparts, do full routing math, emit coef[8] -------
__global__ __launch_bounds__(64) void coeff_k(const float* __restrict__ Mpart,
                                              float* __restrict__ coefb) {
    int n = blockIdx.x;
    int c = threadIdx.x;
    float M[36];
#pragma unroll
    for (int q = 0; q < 36; ++q) M[q] = 0.f;
    for (int s = 0; s < SPL; ++s) {
        const float* mp = Mpart + (((size_t)n * SPL + s) * 64 + c) * 36;
#pragma unroll
        for (int q = 0; q < 36; ++q) M[q] += mp[q];
    }
    float rs[8];
#pragma unroll
    for (int i = 0; i < 8; ++i) rs[i] = 0.f;
    {
        int idx2 = 0;
#pragma unroll
        for (int i = 0; i < 8; ++i)
#pragma unroll
            for (int j = i; j < 8; ++j, ++idx2) {
                rs[i] += M[idx2];
                if (j > i) rs[j] += M[idx2];
            }
    }
    float sumAll = 0.f;
#pragma unroll
    for (int i = 0; i < 8; ++i) sumAll += rs[i];
    float sqn1 = sumAll * (1.f / 64.f);
    float binv = 1.f / (8.f * (1.f + sqn1));
    float bv[8], mx = -1e30f;
#pragma unroll
    for (int i = 0; i < 8; ++i) { bv[i] = rs[i] * binv; mx = fmaxf(mx, bv[i]); }
    float e[8], se = 0.f;
#pragma unroll
    for (int i = 0; i < 8; ++i) { e[i] = expf(bv[i] - mx); se += e[i]; }
    float sinv = 1.f / se;
    float ci_[8];
#pragma unroll
    for (int i = 0; i < 8; ++i) ci_[i] = e[i] * sinv;
    float sqn2 = 0.f;
    {
        int idx2 = 0;
#pragma unroll
        for (int i = 0; i < 8; ++i)
#pragma unroll
            for (int j = i; j < 8; ++j, ++idx2)
                sqn2 += ((j > i) ? 2.f : 1.f) * ci_[i] * ci_[j] * M[idx2];
    }
    float scale = 1.f / (1.f + sqn2);
#pragma unroll
    for (int i = 0; i < 8; ++i) coefb[((size_t)n * 64 + c) * 8 + i] = ci_[i] * scale;
}

// -------- out_k: v(l) = sum_i coef_i * H_i(l); gram-style broadcast layout ----
// c = tid&63, sub = tid>>6; output staged through LDS for coalesced stores.
__global__ __launch_bounds__(256) void out_k(const float* __restrict__ h2,
                                             const float* __restrict__ sq,
                                             const float* __restrict__ wA,
                                             const float* __restrict__ bA,
                                             const float* __restrict__ coefb,
                                             float* __restrict__ out) {
    __shared__ __align__(16) float hs[64 * 36];
    __shared__ __align__(16) float vout[64 * 36];
    __shared__ float invsh[64];
    int n = blockIdx.x / OSPL;
    int s = blockIdx.x - n * OSPL;
    int c = threadIdx.x & 63;
    int sub = threadIdx.x >> 6;
    if (threadIdx.x < 64) invsh[threadIdx.x] = 1.f / (1.f + sq[n * 64 + threadIdx.x]);
    float wreg[24];
#pragma unroll
    for (int q = 0; q < 24; ++q) wreg[q] = wA[c * 24 + q];
    float biasc = bA[c];
    float coef[8];
#pragma unroll
    for (int i = 0; i < 8; ++i) coef[i] = coefb[((size_t)n * 64 + c) * 8 + i];
    const float* h2n = h2 + (size_t)n * 64 * L_LEN;
    int lsub = sub * 8;

    for (int t = s; t < NTT; t += OSPL) {
        int l0 = t * TRT;
        __syncthreads();   // prior store phase done with vout; prior load's hs free
        for (int idx = threadIdx.x; idx < 64 * 34; idx += 256) {
            int qr = idx / 34;
            int j = idx - qr * 34;
            int l = l0 + j - 1;
            hs[qr * 36 + j] = (l >= 0 && l < L_LEN) ? h2n[(size_t)qr * L_LEN + l] * invsh[qr] : 0.f;
        }
        __syncthreads();
        int lbase = l0 + lsub;
        if (lbase < L_LEN) {
            float v[8];
#pragma unroll
            for (int m = 0; m < 8; ++m) v[m] = 0.f;
#pragma unroll
            for (int i = 0; i < 8; ++i) {
                float Hi[8];
#pragma unroll
                for (int m = 0; m < 8; ++m) Hi[m] = biasc;
#pragma unroll
                for (int p = 0; p < 8; ++p) {
                    const float* r = &hs[(8 * i + p) * 36 + lsub];
                    float4 ra = *(const float4*)r;
                    float4 rb = *(const float4*)(r + 4);
                    float2 rc = *(const float2*)(r + 8);
                    float rr[10] = {ra.x, ra.y, ra.z, ra.w, rb.x, rb.y, rb.z, rb.w, rc.x, rc.y};
                    float w0 = wreg[p * 3], w1 = wreg[p * 3 + 1], w2v = wreg[p * 3 + 2];
#pragma unroll
                    for (int m = 0; m < 8; ++m)
                        Hi[m] += w0 * rr[m] + w1 * rr[m + 1] + w2v * rr[m + 2];
                }
                float cw = coef[i];
#pragma unroll
                for (int m = 0; m < 8; ++m) v[m] += cw * Hi[m];
            }
#pragma unroll
            for (int m = 0; m < 8; ++m) vout[c * 36 + lsub + m] = v[m];
        }
        __syncthreads();
        // coalesced store: 64 rows x 8 float4; 4500 % 4 == 0 so guard per-float4
#pragma unroll
        for (int it = 0; it < 2; ++it) {
            int fidx = threadIdx.x + it * 256;
            int cc = fidx >> 3;
            int qq = fidx & 7;
            int l = l0 + qq * 4;
            if (l < L_LEN)
                *(float4*)(out + ((size_t)n * 64 + cc) * L_LEN + l) =
                    *(const float4*)&vout[cc * 36 + qq * 4];
        }
    }
}

extern "C" void kernel_launch(void* const* d_in, const int* in_sizes, int n_in,
                              void* d_out, int out_size, void* d_ws, size_t ws_size,
                              hipStream_t stream) {
    const float* x  = (const float*)d_in[0];
    const float* w1 = (const float*)d_in[1];
    const float* w2 = (const float*)d_in[2];
    const float* wA = (const float*)d_in[3];
    const float* bA = (const float*)d_in[4];
    float* out = (float*)d_out;
    char* ws = (char*)d_ws;
    const size_t HB = (size_t)64 * 64 * L_LEN * 4;   // 73,728,000 B
    float* h1    = (float*)ws;                        // dead after conv2
    float* h2    = (float*)(ws + HB);
    float* sq    = (float*)(ws + 2 * HB);             // 16 KB
    float* w2t   = (float*)(ws + 2 * HB + 16384);     // 80 KB
    float* Mpart = h1;                                // overlay (16*64*64*36*4 = 9.4 MB)
    float* coefb = (float*)(ws + 16 * 1024 * 1024);   // overlay in h1 past Mpart

    hipMemsetAsync(sq, 0, 64 * 64 * sizeof(float), stream);
    prep_w2t_k<<<80, 256, 0, stream>>>(w2, w2t);
    conv1_k<<<4096, 256, 0, stream>>>(x, w1, h1);
    conv2_k<<<64 * NT2, 256, 0, stream>>>(h1, w2t, h2, sq);
    gram_k<<<64 * SPL, 256, 0, stream>>>(h2, sq, wA, bA, Mpart);
    coeff_k<<<64, 64, 0, stream>>>(Mpart, coefb);
    out_k<<<64 * OSPL, 256, 0, stream>>>(h2, sq, wA, bA, coefb, out);
}

// Round 4
// 870.964 us; speedup vs baseline: 1.6176x; 1.6176x over previous
//
#include <hip/hip_runtime.h>
#include <math.h>

#define L_LEN 4500
#define T2 128
#define NT2 36    // ceil(4500/128)
#define TRT 32    // l-span per tile in routing kernels
#define NTT 141   // ceil(4500/32)
#define SPL 16    // l-splits for gram_k

// ---------------- prep: transpose conv2 weights to [cin][g][k] ----------------
__global__ void prep_w2t_k(const float* __restrict__ w2, float* __restrict__ w2t) {
    int i = blockIdx.x * 256 + threadIdx.x;
    if (i < 64 * 64 * 5) {
        int k = i / 320;
        int r = i - k * 320;
        int c = r / 5;
        int g = r - c * 5;
        w2t[(c * 5 + g) * 64 + k] = w2[i];
    }
}

// ---------------- conv1: x (64,1,L) -> h1 (64,64,L), k=7, SAME ----------------
__global__ __launch_bounds__(256) void conv1_k(const float* __restrict__ x,
                                               const float* __restrict__ w1,
                                               float* __restrict__ h1) {
    int n = blockIdx.x >> 6, k = blockIdx.x & 63;
    float w[7];
#pragma unroll
    for (int g = 0; g < 7; ++g) w[g] = w1[k * 7 + g];
    const float* xr = x + (size_t)n * L_LEN;
    float* hr = h1 + ((size_t)n * 64 + k) * L_LEN;
    for (int l = threadIdx.x; l < L_LEN; l += 256) {
        float a = 0.f;
#pragma unroll
        for (int g = 0; g < 7; ++g) {
            int p = l + g - 3;
            if (p >= 0 && p < L_LEN) a += w[g] * xr[p];
        }
        hr[l] = a;
    }
}

// ------- conv2: h1 (64,64,L) -> h2 (64,64,L), k=5, SAME; + sumsq atomics ------
__global__ __launch_bounds__(256) void conv2_k(const float* __restrict__ h1,
                                               const float* __restrict__ w2t,
                                               float* __restrict__ h2,
                                               float* __restrict__ sq) {
    __shared__ float h1s[64][T2 + 4];
    __shared__ float sqred[4][64];
    int n = blockIdx.x / NT2;
    int t = blockIdx.x - n * NT2;
    int l0 = t * T2;
    const float* h1n = h1 + (size_t)n * 64 * L_LEN;
    for (int idx = threadIdx.x; idx < 64 * (T2 + 4); idx += 256) {
        int ci = idx / (T2 + 4);
        int j = idx - ci * (T2 + 4);
        int l = l0 + j - 2;
        h1s[ci][j] = (l >= 0 && l < L_LEN) ? h1n[(size_t)ci * L_LEN + l] : 0.f;
    }
    __syncthreads();
    int k = threadIdx.x & 63;
    int lg = threadIdx.x >> 6;
    int base = lg * 32;
    float acc[32];
#pragma unroll
    for (int m = 0; m < 32; ++m) acc[m] = 0.f;
    for (int ci = 0; ci < 64; ++ci) {
        const float* wr = w2t + ci * 320 + k;
        float w0 = wr[0], w1 = wr[64], w2v = wr[128], w3 = wr[192], w4 = wr[256];
        float v[36];
#pragma unroll
        for (int j = 0; j < 36; ++j) v[j] = h1s[ci][base + j];
#pragma unroll
        for (int m = 0; m < 32; ++m)
            acc[m] += w0 * v[m] + w1 * v[m + 1] + w2v * v[m + 2] + w3 * v[m + 3] + w4 * v[m + 4];
    }
    float s = 0.f;
    float* h2r = h2 + ((size_t)n * 64 + k) * L_LEN;
#pragma unroll
    for (int m = 0; m < 32; ++m) {
        int l = l0 + base + m;
        if (l < L_LEN) { h2r[l] = acc[m]; s += acc[m] * acc[m]; }
    }
    sqred[lg][k] = s;
    __syncthreads();
    if (threadIdx.x < 64) {
        float tot = sqred[0][threadIdx.x] + sqred[1][threadIdx.x] +
                    sqred[2][threadIdx.x] + sqred[3][threadIdx.x];
        atomicAdd(&sq[n * 64 + threadIdx.x], tot);
    }
}

// ------ gram_k: per (n, l-split) accumulate Gram M[36] for all 64 channels ----
// c = tid&63 (lane -> channel, LDS reads wave-broadcast), sub = tid>>6.
// m=4 per pass (2 passes/tile) keeps H to 32 regs -> no scratch spill.
// 4500 % 4 == 0 -> the wave-uniform lbase guard is exact, no tail masking.
__global__ __launch_bounds__(256) void gram_k(const float* __restrict__ h2,
                                              const float* __restrict__ sq,
                                              const float* __restrict__ wA,
                                              const float* __restrict__ bA,
                                              float* __restrict__ Mpart) {
    __shared__ __align__(16) float smem[4 * 64 * 36];   // hs (64*36) overlaid by Msh
    __shared__ float invsh[64];
    float* hs = smem;
    int n = blockIdx.x / SPL;
    int s = blockIdx.x - n * SPL;
    int c = threadIdx.x & 63;
    int sub = threadIdx.x >> 6;
    if (threadIdx.x < 64) invsh[threadIdx.x] = 1.f / (1.f + sq[n * 64 + threadIdx.x]);
    float wreg[24];
#pragma unroll
    for (int q = 0; q < 24; ++q) wreg[q] = wA[c * 24 + q];
    float biasc = bA[c];
    const float* h2n = h2 + (size_t)n * 64 * L_LEN;
    float M[36];
#pragma unroll
    for (int q = 0; q < 36; ++q) M[q] = 0.f;

    for (int t = s; t < NTT; t += SPL) {
        int l0 = t * TRT;
        __syncthreads();
        for (int idx = threadIdx.x; idx < 64 * 34; idx += 256) {
            int qr = idx / 34;
            int j = idx - qr * 34;
            int l = l0 + j - 1;
            hs[qr * 36 + j] = (l >= 0 && l < L_LEN) ? h2n[(size_t)qr * L_LEN + l] * invsh[qr] : 0.f;
        }
        __syncthreads();
#pragma unroll
        for (int half = 0; half < 2; ++half) {
            int lsub = half * 16 + sub * 4;
            int lbase = l0 + lsub;           // wave-uniform; multiples of 4
            if (lbase >= L_LEN) continue;
            float H[32];                     // H[i*4+m], compile-time indices only
#pragma unroll
            for (int q = 0; q < 32; ++q) H[q] = biasc;
#pragma unroll
            for (int i = 0; i < 8; ++i) {
#pragma unroll
                for (int p = 0; p < 8; ++p) {
                    const float* r = &hs[(8 * i + p) * 36 + lsub];
                    float4 ra = *(const float4*)r;
                    float2 rc = *(const float2*)(r + 4);
                    float rr[6] = {ra.x, ra.y, ra.z, ra.w, rc.x, rc.y};
                    float w0 = wreg[p * 3], w1 = wreg[p * 3 + 1], w2v = wreg[p * 3 + 2];
#pragma unroll
                    for (int m = 0; m < 4; ++m)
                        H[i * 4 + m] += w0 * rr[m] + w1 * rr[m + 1] + w2v * rr[m + 2];
                }
            }
            int idx2 = 0;
#pragma unroll
            for (int i = 0; i < 8; ++i)
#pragma unroll
                for (int j = i; j < 8; ++j, ++idx2) {
                    float a = 0.f;
#pragma unroll
                    for (int m = 0; m < 4; ++m) a += H[i * 4 + m] * H[j * 4 + m];
                    M[idx2] += a;
                }
        }
    }
    __syncthreads();       // all compute done; hs dead -> reuse smem as Msh
    float* Msh = smem;     // [4][64][36]
#pragma unroll
    for (int q = 0; q < 36; ++q) Msh[(sub * 64 + c) * 36 + q] = M[q];
    __syncthreads();
    for (int idx = threadIdx.x; idx < 64 * 36; idx += 256) {
        int cc = idx / 36;
        int q = idx - cc * 36;
        float tot = Msh[(0 * 64 + cc) * 36 + q] + Msh[(1 * 64 + cc) * 36 + q] +
                    Msh[(2 * 64 + cc) * 36 + q] + Msh[(3 * 64 + cc) * 36 + q];
        Mpart[(((size_t)n * SPL + s) * 64 + cc) * 36 + q] = tot;
    }
}

// ---------- coeff_k: reduce Mparts, do full routing math, emit coef[8] -------
__global__ __launch_bounds__(64) void coeff_k(const float* __restrict__ Mpart,
                                              float* __restrict__ coefb) {
    int n = blockIdx.x;
    int c = threadIdx.x;
    float M[36];
#pragma unroll
    for (int q = 0; q < 36; ++q) M[q] = 0.f;
    for (int s = 0; s < SPL; ++s) {
        const float* mp = Mpart + (((size_t)n * SPL + s) * 64 + c) * 36;
#pragma unroll
        for (int q = 0; q < 36; ++q) M[q] += mp[q];
    }
    float rs[8];
#pragma unroll
    for (int i = 0; i < 8; ++i) rs[i] = 0.f;
    {
        int idx2 = 0;
#pragma unroll
        for (int i = 0; i < 8; ++i)
#pragma unroll
            for (int j = i; j < 8; ++j, ++idx2) {
                rs[i] += M[idx2];
                if (j > i) rs[j] += M[idx2];
            }
    }
    float sumAll = 0.f;
#pragma unroll
    for (int i = 0; i < 8; ++i) sumAll += rs[i];
    float sqn1 = sumAll * (1.f / 64.f);
    float binv = 1.f / (8.f * (1.f + sqn1));
    float bv[8], mx = -1e30f;
#pragma unroll
    for (int i = 0; i < 8; ++i) { bv[i] = rs[i] * binv; mx = fmaxf(mx, bv[i]); }
    float e[8], se = 0.f;
#pragma unroll
    for (int i = 0; i < 8; ++i) { e[i] = expf(bv[i] - mx); se += e[i]; }
    float sinv = 1.f / se;
    float ci_[8];
#pragma unroll
    for (int i = 0; i < 8; ++i) ci_[i] = e[i] * sinv;
    float sqn2 = 0.f;
    {
        int idx2 = 0;
#pragma unroll
        for (int i = 0; i < 8; ++i)
#pragma unroll
            for (int j = i; j < 8; ++j, ++idx2)
                sqn2 += ((j > i) ? 2.f : 1.f) * ci_[i] * ci_[j] * M[idx2];
    }
    float scale = 1.f / (1.f + sqn2);
#pragma unroll
    for (int i = 0; i < 8; ++i) coefb[((size_t)n * 64 + c) * 8 + i] = ci_[i] * scale;
}

// -------- out_k: one (n, l-tile) per block; c = lane broadcast layout --------
// v(l) = sum_i coef_i * H_i(l); vout staged in LDS for coalesced float4 stores.
__global__ __launch_bounds__(256) void out_k(const float* __restrict__ h2,
                                             const float* __restrict__ sq,
                                             const float* __restrict__ wA,
                                             const float* __restrict__ bA,
                                             const float* __restrict__ coefb,
                                             float* __restrict__ out) {
    __shared__ __align__(16) float hs[64 * 36];
    __shared__ __align__(16) float vout[64 * 36];
    __shared__ float invsh[64];
    int n = blockIdx.x / NTT;
    int t = blockIdx.x - n * NTT;
    int l0 = t * TRT;
    int c = threadIdx.x & 63;
    int sub = threadIdx.x >> 6;
    int lsub = sub * 8;
    if (threadIdx.x < 64) invsh[threadIdx.x] = 1.f / (1.f + sq[n * 64 + threadIdx.x]);
    float wreg[24];
#pragma unroll
    for (int q = 0; q < 24; ++q) wreg[q] = wA[c * 24 + q];
    float biasc = bA[c];
    float coef[8];
#pragma unroll
    for (int i = 0; i < 8; ++i) coef[i] = coefb[((size_t)n * 64 + c) * 8 + i];
    const float* h2n = h2 + (size_t)n * 64 * L_LEN;
    __syncthreads();
    for (int idx = threadIdx.x; idx < 64 * 34; idx += 256) {
        int qr = idx / 34;
        int j = idx - qr * 34;
        int l = l0 + j - 1;
        hs[qr * 36 + j] = (l >= 0 && l < L_LEN) ? h2n[(size_t)qr * L_LEN + l] * invsh[qr] : 0.f;
    }
    __syncthreads();
    {
        float v[8];
#pragma unroll
        for (int m = 0; m < 8; ++m) v[m] = 0.f;
#pragma unroll
        for (int i = 0; i < 8; ++i) {
            float Hi[8];
#pragma unroll
            for (int m = 0; m < 8; ++m) Hi[m] = biasc;
#pragma unroll
            for (int p = 0; p < 8; ++p) {
                const float* r = &hs[(8 * i + p) * 36 + lsub];
                float4 ra = *(const float4*)r;
                float4 rb = *(const float4*)(r + 4);
                float2 rc = *(const float2*)(r + 8);
                float rr[10] = {ra.x, ra.y, ra.z, ra.w, rb.x, rb.y, rb.z, rb.w, rc.x, rc.y};
                float w0 = wreg[p * 3], w1 = wreg[p * 3 + 1], w2v = wreg[p * 3 + 2];
#pragma unroll
                for (int m = 0; m < 8; ++m)
                    Hi[m] += w0 * rr[m] + w1 * rr[m + 1] + w2v * rr[m + 2];
            }
            float cw = coef[i];
#pragma unroll
            for (int m = 0; m < 8; ++m) v[m] += cw * Hi[m];
        }
#pragma unroll
        for (int m = 0; m < 8; ++m) vout[c * 36 + lsub + m] = v[m];
    }
    __syncthreads();
    // coalesced store: 64 rows x 8 float4; 4500 % 4 == 0 so per-float4 guard exact
#pragma unroll
    for (int it = 0; it < 2; ++it) {
        int fidx = threadIdx.x + it * 256;
        int cc = fidx >> 3;
        int qq = fidx & 7;
        int l = l0 + qq * 4;
        if (l < L_LEN)
            *(float4*)(out + ((size_t)n * 64 + cc) * L_LEN + l) =
                *(const float4*)&vout[cc * 36 + qq * 4];
    }
}

extern "C" void kernel_launch(void* const* d_in, const int* in_sizes, int n_in,
                              void* d_out, int out_size, void* d_ws, size_t ws_size,
                              hipStream_t stream) {
    const float* x  = (const float*)d_in[0];
    const float* w1 = (const float*)d_in[1];
    const float* w2 = (const float*)d_in[2];
    const float* wA = (const float*)d_in[3];
    const float* bA = (const float*)d_in[4];
    float* out = (float*)d_out;
    char* ws = (char*)d_ws;
    const size_t HB = (size_t)64 * 64 * L_LEN * 4;   // 73,728,000 B
    float* h1    = (float*)ws;                        // dead after conv2
    float* h2    = (float*)(ws + HB);
    float* sq    = (float*)(ws + 2 * HB);             // 16 KB
    float* w2t   = (float*)(ws + 2 * HB + 16384);     // 80 KB
    float* Mpart = h1;                                // overlay (16*64*64*36*4 = 9.4 MB)
    float* coefb = (float*)(ws + 16 * 1024 * 1024);   // overlay in h1 past Mpart

    hipMemsetAsync(sq, 0, 64 * 64 * sizeof(float), stream);
    prep_w2t_k<<<80, 256, 0, stream>>>(w2, w2t);
    conv1_k<<<4096, 256, 0, stream>>>(x, w1, h1);
    conv2_k<<<64 * NT2, 256, 0, stream>>>(h1, w2t, h2, sq);
    gram_k<<<64 * SPL, 256, 0, stream>>>(h2, sq, wA, bA, Mpart);
    coeff_k<<<64, 64, 0, stream>>>(Mpart, coefb);
    out_k<<<64 * NTT, 256, 0, stream>>>(h2, sq, wA, bA, coefb, out);
}